// Round 7
// baseline (212.827 us; speedup 1.0000x reference)
//
#include <hip/hip_runtime.h>
#include <stdint.h>

#define DI __device__ __forceinline__

typedef __attribute__((ext_vector_type(8))) __bf16 bf16x8;
typedef __attribute__((ext_vector_type(8))) short short8;
typedef __attribute__((ext_vector_type(4))) float f32x4;
typedef __attribute__((ext_vector_type(16))) float f32x16;

DI unsigned short f2bf(float f) {
    union { float f; uint32_t u; } v; v.f = f;
    uint32_t r = v.u + 0x7FFFu + ((v.u >> 16) & 1u);   // RNE
    return (unsigned short)(r >> 16);
}
DI uint32_t pk2(float a, float b) {        // {lo=bf16(a), hi=bf16(b)} in 1 instr
    uint32_t r;
    asm("v_cvt_pk_bf16_f32 %0, %1, %2" : "=v"(r) : "v"(a), "v"(b));
    return r;
}
DI float bflo(uint32_t w) { union { uint32_t u; float f; } x; x.u = w << 16; return x.f; }
DI float bfhi(uint32_t w) { union { uint32_t u; float f; } x; x.u = w & 0xffff0000u; return x.f; }
DI bf16x8 asb(short8 s) { union { short8 s; bf16x8 b; } u; u.s = s; return u.b; }
DI bf16x8 asb4(uint32_t a, uint32_t b, uint32_t c, uint32_t d) {
    union { uint32_t u[4]; bf16x8 b; } x; x.u[0] = a; x.u[1] = b; x.u[2] = c; x.u[3] = d; return x.b;
}
DI void gload16(const void* g, void* l) {
    __builtin_amdgcn_global_load_lds(
        (const __attribute__((address_space(1))) void*)g,
        (__attribute__((address_space(3))) void*)l, 16, 0, 0);
}
DI int swzc(int c) { return c ^ ((c >> 3) & 7); }   // XOR chunk swizzle within a row

// ------------- fused prep: cast x/Wqkv/Wout to bf16 + RoPE table -----------
__global__ __launch_bounds__(256) void prepk(
    const float* __restrict__ x, const float* __restrict__ Wqkv,
    const float* __restrict__ Wout,
    unsigned short* __restrict__ xb, unsigned short* __restrict__ wqkvb,
    unsigned short* __restrict__ woutb,
    float* __restrict__ cosT, float* __restrict__ sinT) {
    const int bid = blockIdx.x, tid = threadIdx.x;
    if (bid < 8192) {
        const float* in; unsigned short* out; int i;
        if (bid < 4096)      { in = x;    out = xb;    i = bid * 256 + tid; }
        else if (bid < 7168) { in = Wqkv; out = wqkvb; i = (bid - 4096) * 256 + tid; }
        else                 { in = Wout; out = woutb; i = (bid - 7168) * 256 + tid; }
        float4 v = ((const float4*)in)[i];
        union { unsigned short u[4]; uint2 q; } p;
        p.u[0] = f2bf(v.x); p.u[1] = f2bf(v.y); p.u[2] = f2bf(v.z); p.u[3] = f2bf(v.w);
        ((uint2*)out)[i] = p.q;
    } else {
        int i = (bid - 8192) * 256 + tid;       // 65536 total
        int n = i >> 5, d = i & 31;
        float inv = powf(10000.0f, -(float)(2 * d) * (1.0f / 64.0f));
        float a = (float)n * inv;
        float s, c;
        sincosf(a, &s, &c);
        cosT[i] = c; sinT[i] = s;
    }
}

// ---------------------- GEMM C = A * Bt^T  (bf16 MFMA) ---------------------
// Tile BM x 128, 4 waves (2x2), BK=32, 16x16x32 bf16 MFMA (m97 shape, R1-proven).
// MODE 0 (BM=128): qkv epilogue (RoPE; Q scaled by log2e/8; V transposed via
//                  LDS with key-permuted layout: slot s holds key swap23(s))
// MODE 1 (BM=64):  out epilogue (+bias, fp32 store)
template <int MODE, int BM>
__global__ __launch_bounds__(256) void gemm_bt(
    const unsigned short* __restrict__ A, const unsigned short* __restrict__ Bt,
    int M, int N, int K,
    unsigned short* __restrict__ Qbuf, unsigned short* __restrict__ Kbuf,
    unsigned short* __restrict__ Vt,
    const float* __restrict__ cosT, const float* __restrict__ sinT,
    float* __restrict__ Cout, const float* __restrict__ bias) {
    constexpr int WM = BM / 2;       // rows per wave
    constexpr int MI = WM / 16;      // A-frag count per wave
    __shared__ __align__(16) unsigned short As[BM * 32];
    __shared__ __align__(16) unsigned short Bs[128 * 32];
    const int tid = threadIdx.x;
    const int wave = tid >> 6, lane = tid & 63, g = lane >> 4, li = lane & 15;
    const int wr = wave >> 1, wc = wave & 1;
    const int m0 = blockIdx.y * BM, n0 = blockIdx.x * 128;

    f32x4 acc[MI][4] = {};
    const int nK = K >> 5;
    for (int kk = 0; kk < nK; ++kk) {
#pragma unroll
        for (int i = 0; i < BM / 64; ++i) {     // A tile: BM*4 chunks of 16B
            int cb = i * 256 + wave * 64;
            int c = cb + lane;
            int r = c >> 2, k0 = (c & 3) * 8;
            gload16(A + (size_t)(m0 + r) * K + kk * 32 + k0, &As[cb * 8]);
        }
#pragma unroll
        for (int i = 0; i < 2; ++i) {           // B tile: 512 chunks
            int cb = i * 256 + wave * 64;
            int c = cb + lane;
            int r = c >> 2, k0 = (c & 3) * 8;
            gload16(Bt + (size_t)(n0 + r) * K + kk * 32 + k0, &Bs[cb * 8]);
        }
        __syncthreads();
        short8 af[MI], bf[4];
#pragma unroll
        for (int mi = 0; mi < MI; ++mi)
            af[mi] = *(const short8*)&As[(wr * WM + mi * 16 + li) * 32 + g * 8];
#pragma unroll
        for (int ni = 0; ni < 4; ++ni)
            bf[ni] = *(const short8*)&Bs[(wc * 64 + ni * 16 + li) * 32 + g * 8];
#pragma unroll
        for (int mi = 0; mi < MI; ++mi)
#pragma unroll
            for (int ni = 0; ni < 4; ++ni)
                acc[mi][ni] = __builtin_amdgcn_mfma_f32_16x16x32_bf16(
                    asb(af[mi]), asb(bf[ni]), acc[mi][ni], 0, 0, 0);
        __syncthreads();
    }

    if (MODE == 1) {
#pragma unroll
        for (int mi = 0; mi < MI; ++mi) {
            int row = m0 + wr * WM + mi * 16 + 4 * g;
#pragma unroll
            for (int ni = 0; ni < 4; ++ni) {
                int col = n0 + wc * 64 + ni * 16 + li;
                float b = bias[col];
#pragma unroll
                for (int r = 0; r < 4; ++r)
                    Cout[(size_t)(row + r) * N + col] = acc[mi][ni][r] + b;
            }
        }
    } else {
        // three = fb/1024 is block-uniform; hh differs per wave-column
        const int fb = n0 + wc * 64;
        const int three = fb >> 10;
        const int hh = (fb & 1023) >> 6;
        const int bq = m0 >> 11;
        const int nb0 = m0 & 2047;
        const size_t bh = (size_t)(bq * 16 + hh);
        if (three < 2) {
            // Q/K with RoPE; Q scaled by log2e/8 (base-2 softmax fold)
#pragma unroll
            for (int mi = 0; mi < MI; ++mi) {
#pragma unroll
                for (int r = 0; r < 4; ++r) {
                    int n = nb0 + wr * WM + mi * 16 + 4 * g + r;
                    float v0 = acc[mi][0][r], v1 = acc[mi][1][r];
                    float v2 = acc[mi][2][r], v3 = acc[mi][3][r];
                    float c0 = cosT[n * 32 + li],      s0 = sinT[n * 32 + li];
                    float c1 = cosT[n * 32 + 16 + li], s1 = sinT[n * 32 + 16 + li];
                    float o0 = v0 * c0 - v2 * s0;
                    float o2 = v2 * c0 + v0 * s0;
                    float o1 = v1 * c1 - v3 * s1;
                    float o3 = v3 * c1 + v1 * s1;
                    if (three == 0) {
                        const float qs = 0.18033688f;  // 0.125 * log2(e)
                        o0 *= qs; o1 *= qs; o2 *= qs; o3 *= qs;
                    }
                    unsigned short* dst = (three == 0 ? Qbuf : Kbuf) + (bh * 2048 + n) * 64;
                    dst[li] = f2bf(o0); dst[16 + li] = f2bf(o1);
                    dst[32 + li] = f2bf(o2); dst[48 + li] = f2bf(o3);
                }
            }
        } else {
            // V: per-wave transpose via LDS (reuse As), with key-permutation
            // swap23 within each 16-token group (PV sigma-layout, see attnk)
            unsigned short* vtw = As + wave * 1024;        // [64 d][16 slots]
            const int gsw = ((g & 1) << 1) | (g >> 1);     // swap 2-bit halves
#pragma unroll
            for (int mi = 0; mi < MI; ++mi) {
                __syncthreads();               // prev-mi reads fully done
#pragma unroll
                for (int ni = 0; ni < 4; ++ni)
#pragma unroll
                    for (int r = 0; r < 4; ++r)
                        vtw[(ni * 16 + li) * 16 + 4 * gsw + r] = f2bf(acc[mi][ni][r]);
                __syncthreads();               // transpose writes visible
                uint4 lo = *(const uint4*)&vtw[lane * 16];
                uint4 hi = *(const uint4*)&vtw[lane * 16 + 8];
                int nbase = nb0 + wr * WM + mi * 16;
                unsigned short* dst = Vt + (bh * 64 + lane) * 2048 + nbase;
                *(uint4*)dst = lo;
                *(uint4*)(dst + 8) = hi;
            }
        }
    }
}

// ------------------------------ attention ---------------------------------
// KV-split x2: block (bh, s, qt) handles keys [s*1024, s*1024+1024) for 128
// q-rows. Fixed-base softmax (p = exp2(s)) -> partials combine by plain sum.
// Grid 1024 = 4 blocks/CU (4 waves/SIMD, 2x R6 occupancy).
__global__ __launch_bounds__(256) void attnk(
    const unsigned short* __restrict__ Qb, const unsigned short* __restrict__ Kb,
    const unsigned short* __restrict__ Vt, unsigned short* __restrict__ Op,
    float* __restrict__ lp) {
    __shared__ __align__(16) unsigned short Ks[2][64 * 64];
    __shared__ __align__(16) unsigned short Vs[2][64 * 64];
    const int tid = threadIdx.x, wave = tid >> 6, lane = tid & 63;
    const int h = lane >> 5, li = lane & 31;

    // XCD-bijective swizzle: 1024 blocks / 8 XCDs -> 4 heads per XCD (2MB L2)
    const int fid = blockIdx.y * 32 + blockIdx.x;
    const int logical = (fid & 7) * 128 + (fid >> 3);
    const int bh = logical >> 5;
    const int s  = (logical >> 4) & 1;
    const int qt = logical & 15;
    const int q0 = qt * 128 + wave * 32;

    // Q B-frags: lane holds Q[q0+li][16c + 8h + j]  (pre-scaled by log2e/8)
    bf16x8 qf[4];
    const unsigned short* qp = Qb + ((size_t)bh * 2048 + q0 + li) * 64;
#pragma unroll
    for (int c = 0; c < 4; ++c) qf[c] = asb(*(const short8*)(qp + c * 16 + h * 8));

    // staging geometry: chunk c in [0,512): row=c>>3, cc=c&7; tiles s*16+kti
    const uint4* kg = (const uint4*)(Kb + (size_t)bh * 2048 * 64) + (size_t)s * 16 * 512;
    const uint4* vg = (const uint4*)Vt;
    const int r0 = tid >> 3, r1 = (tid + 256) >> 3, cc = tid & 7;
    const int sw0 = swzc(tid) * 8, sw1 = swzc(tid + 256) * 8;
    const size_t vrow0 = ((size_t)bh * 64 + r0) * 256 + cc + (size_t)s * 16 * 8;
    const size_t vrow1 = ((size_t)bh * 64 + r1) * 256 + cc + (size_t)s * 16 * 8;

    uint4 kr0, kr1, vr0, vr1;

    f32x16 o0 = {}, o1 = {};
    float l_ = 0.f;

    // prologue: load+stage tile 0; after barrier, issue loads for tile 1
    kr0 = kg[tid]; kr1 = kg[256 + tid];
    vr0 = vg[vrow0]; vr1 = vg[vrow1];
    *(uint4*)&Ks[0][sw0] = kr0; *(uint4*)&Ks[0][sw1] = kr1;
    *(uint4*)&Vs[0][sw0] = vr0; *(uint4*)&Vs[0][sw1] = vr1;
    __syncthreads();
    kr0 = kg[512 + tid]; kr1 = kg[512 + 256 + tid];
    vr0 = vg[vrow0 + 8]; vr1 = vg[vrow1 + 8];

    for (int kti = 0; kti < 16; ++kti) {
        const int cur = kti & 1;

        // S^T = K Q^T : col=li=q, row=(r&3)+8*(r>>2)+4h = key
        f32x16 s0 = {}, s1 = {};
#pragma unroll
        for (int c = 0; c < 4; ++c) {
            int ch = 2 * c + h;
            bf16x8 k0 = asb(*(const short8*)&Ks[cur][li * 64 + ((ch ^ (li & 7)) * 8)]);
            bf16x8 k1 = asb(*(const short8*)&Ks[cur][(32 + li) * 64 + ((ch ^ (li & 7)) * 8)]);
            s0 = __builtin_amdgcn_mfma_f32_32x32x16_bf16(k0, qf[c], s0, 0, 0, 0);
            s1 = __builtin_amdgcn_mfma_f32_32x32x16_bf16(k1, qf[c], s1, 0, 0, 0);
        }

        // fixed-base softmax: p = exp2(s); lane-local partial sum
        float sm0 = 0.f, sm1 = 0.f;
#pragma unroll
        for (int r = 0; r < 16; ++r) {
            float p0 = __builtin_exp2f(s0[r]); s0[r] = p0; sm0 += p0;
            float p1 = __builtin_exp2f(s1[r]); s1[r] = p1; sm1 += p1;
        }
        l_ += sm0 + sm1;

        // pack P to bf16 words (v_cvt_pk_bf16_f32)
        uint32_t w0[8], w1[8];
#pragma unroll
        for (int m = 0; m < 8; ++m) {
            w0[m] = pk2(s0[2 * m], s0[2 * m + 1]);
            w1[m] = pk2(s1[2 * m], s1[2 * m + 1]);
        }

        // PV: O += P V. sigma-permuted V makes lane's own words the A-frag.
#pragma unroll
        for (int ks = 0; ks < 4; ++ks) {
            const uint32_t* wk = (ks < 2) ? w0 : w1;
            const int sub = (ks & 1) * 4;
            bf16x8 pf = asb4(wk[sub], wk[sub + 1], wk[sub + 2], wk[sub + 3]);
            int ch = 2 * ks + h;
            bf16x8 vf0 = asb(*(const short8*)&Vs[cur][li * 64 + ((ch ^ (li & 7)) * 8)]);
            bf16x8 vf1 = asb(*(const short8*)&Vs[cur][(32 + li) * 64 + ((ch ^ (li & 7)) * 8)]);
            o0 = __builtin_amdgcn_mfma_f32_32x32x16_bf16(pf, vf0, o0, 0, 0, 0);
            o1 = __builtin_amdgcn_mfma_f32_32x32x16_bf16(pf, vf1, o1, 0, 0, 0);
        }

        if (kti < 15) {
            // stage tile kti+1 (regs loaded during THIS tile's compute)
            const int nxt = cur ^ 1;
            *(uint4*)&Ks[nxt][sw0] = kr0; *(uint4*)&Ks[nxt][sw1] = kr1;
            *(uint4*)&Vs[nxt][sw0] = vr0; *(uint4*)&Vs[nxt][sw1] = vr1;
            __syncthreads();   // writes(kti+1) visible; reads(kti) drained
            if (kti < 14) {    // issue loads for tile kti+2 AFTER the barrier
                int nt = kti + 2;
                kr0 = kg[nt * 512 + tid]; kr1 = kg[nt * 512 + 256 + tid];
                vr0 = vg[vrow0 + nt * 8]; vr1 = vg[vrow1 + nt * 8];
            }
        }
    }

    // epilogue: store UNNORMALIZED partial O (bf16) + partial l (f32)
    const size_t obase = ((size_t)s * 32 + bh) * 2048;
#pragma unroll
    for (int r = 0; r < 16; ++r) {
        int qrow = (r & 3) + 8 * (r >> 2) + 4 * h;
        int n = q0 + qrow;
        unsigned short* dst = Op + (obase + n) * 64 + li;
        dst[0]  = f2bf(o0[r]);
        dst[32] = f2bf(o1[r]);
    }
    float lc = l_ + __shfl_xor(l_, 32);
    if (h == 0) lp[obase + q0 + li] = lc;
}

// ------------------------- combine split partials --------------------------
// Obuf[b][n][hh][64] = (O0 + O1) / (l0 + l1), bf16. 524288 threads.
__global__ __launch_bounds__(256) void combk(
    const unsigned short* __restrict__ Op, const float* __restrict__ lp,
    unsigned short* __restrict__ Obuf) {
    int t = blockIdx.x * 256 + threadIdx.x;
    int d8 = t & 7, hh = (t >> 3) & 15, n = (t >> 7) & 2047, b = t >> 18;
    size_t row = ((size_t)(b * 16 + hh)) * 2048 + n;
    float linv = 1.0f / (lp[row] + lp[row + 65536]);
    const uint4 a = *(const uint4*)(Op + row * 64 + d8 * 8);
    const uint4 c = *(const uint4*)(Op + 4194304 + row * 64 + d8 * 8);
    uint4 o;
    o.x = pk2(linv * (bflo(a.x) + bflo(c.x)), linv * (bfhi(a.x) + bfhi(c.x)));
    o.y = pk2(linv * (bflo(a.y) + bflo(c.y)), linv * (bfhi(a.y) + bfhi(c.y)));
    o.z = pk2(linv * (bflo(a.z) + bflo(c.z)), linv * (bfhi(a.z) + bfhi(c.z)));
    o.w = pk2(linv * (bflo(a.w) + bflo(c.w)), linv * (bfhi(a.w) + bfhi(c.w)));
    *(uint4*)(Obuf + ((size_t)(b * 2048 + n)) * 1024 + hh * 64 + d8 * 8) = o;
}

// ------------------------------- launch ------------------------------------
extern "C" void kernel_launch(void* const* d_in, const int* in_sizes, int n_in,
                              void* d_out, int out_size, void* d_ws, size_t ws_size,
                              hipStream_t stream) {
    const float* x    = (const float*)d_in[0];
    const float* Wqkv = (const float*)d_in[1];
    const float* Wout = (const float*)d_in[2];
    const float* bout = (const float*)d_in[3];
    float* out = (float*)d_out;
    char* ws = (char*)d_ws;

    size_t off = 0;
    unsigned short* xb    = (unsigned short*)(ws + off);
    unsigned short* Obuf  = xb;                                      // alias
    off += (size_t)4096 * 1024 * 2;
    unsigned short* wqkvb = (unsigned short*)(ws + off); off += (size_t)3072 * 1024 * 2;
    unsigned short* woutb = (unsigned short*)(ws + off); off += (size_t)1024 * 1024 * 2;
    float* cosT = (float*)(ws + off); off += (size_t)2048 * 32 * 4;
    float* sinT = (float*)(ws + off); off += (size_t)2048 * 32 * 4;
    unsigned short* Qbuf = (unsigned short*)(ws + off); off += (size_t)32 * 2048 * 64 * 2;
    unsigned short* Kbuf = (unsigned short*)(ws + off); off += (size_t)32 * 2048 * 64 * 2;
    unsigned short* Vt   = (unsigned short*)(ws + off); off += (size_t)32 * 64 * 2048 * 2;
    unsigned short* Op   = (unsigned short*)(ws + off); off += (size_t)2 * 32 * 2048 * 64 * 2;
    float* lp            = (float*)(ws + off);          off += (size_t)2 * 32 * 2048 * 4;

    prepk<<<8448, 256, 0, stream>>>(x, Wqkv, Wout, xb, wqkvb, woutb, cosT, sinT);

    gemm_bt<0, 128><<<dim3(24, 32), 256, 0, stream>>>(
        xb, wqkvb, 4096, 3072, 1024, Qbuf, Kbuf, Vt, cosT, sinT, nullptr, nullptr);

    attnk<<<dim3(32, 32), 256, 0, stream>>>(Qbuf, Kbuf, Vt, Op, lp);

    combk<<<2048, 256, 0, stream>>>(Op, lp, Obuf);

    gemm_bt<1, 64><<<dim3(8, 64), 256, 0, stream>>>(
        Obuf, woutb, 4096, 1024, 1024, nullptr, nullptr, nullptr, nullptr, nullptr,
        out, bout);
}

// Round 8
// 205.438 us; speedup vs baseline: 1.0360x; 1.0360x over previous
//
#include <hip/hip_runtime.h>
#include <stdint.h>

#define DI __device__ __forceinline__

typedef __attribute__((ext_vector_type(8))) __bf16 bf16x8;
typedef __attribute__((ext_vector_type(8))) short short8;
typedef __attribute__((ext_vector_type(4))) float f32x4;
typedef __attribute__((ext_vector_type(16))) float f32x16;

DI unsigned short f2bf(float f) {
    union { float f; uint32_t u; } v; v.f = f;
    uint32_t r = v.u + 0x7FFFu + ((v.u >> 16) & 1u);   // RNE
    return (unsigned short)(r >> 16);
}
DI uint32_t pk2(float a, float b) {        // {lo=bf16(a), hi=bf16(b)} in 1 instr
    uint32_t r;
    asm("v_cvt_pk_bf16_f32 %0, %1, %2" : "=v"(r) : "v"(a), "v"(b));
    return r;
}
DI float bflo(uint32_t w) { union { uint32_t u; float f; } x; x.u = w << 16; return x.f; }
DI float bfhi(uint32_t w) { union { uint32_t u; float f; } x; x.u = w & 0xffff0000u; return x.f; }
DI bf16x8 asb(short8 s) { union { short8 s; bf16x8 b; } u; u.s = s; return u.b; }
DI bf16x8 asb4(uint32_t a, uint32_t b, uint32_t c, uint32_t d) {
    union { uint32_t u[4]; bf16x8 b; } x; x.u[0] = a; x.u[1] = b; x.u[2] = c; x.u[3] = d; return x.b;
}
DI void gload16(const void* g, void* l) {
    __builtin_amdgcn_global_load_lds(
        (const __attribute__((address_space(1))) void*)g,
        (__attribute__((address_space(3))) void*)l, 16, 0, 0);
}
DI int swzc(int c) { return c ^ ((c >> 3) & 7); }   // XOR chunk swizzle within a row

// ------------- fused prep: cast x/Wqkv/Wout to bf16 + RoPE table -----------
__global__ __launch_bounds__(256) void prepk(
    const float* __restrict__ x, const float* __restrict__ Wqkv,
    const float* __restrict__ Wout,
    unsigned short* __restrict__ xb, unsigned short* __restrict__ wqkvb,
    unsigned short* __restrict__ woutb,
    float* __restrict__ cosT, float* __restrict__ sinT) {
    const int bid = blockIdx.x, tid = threadIdx.x;
    if (bid < 8192) {
        const float* in; unsigned short* out; int i;
        if (bid < 4096)      { in = x;    out = xb;    i = bid * 256 + tid; }
        else if (bid < 7168) { in = Wqkv; out = wqkvb; i = (bid - 4096) * 256 + tid; }
        else                 { in = Wout; out = woutb; i = (bid - 7168) * 256 + tid; }
        float4 v = ((const float4*)in)[i];
        union { unsigned short u[4]; uint2 q; } p;
        p.u[0] = f2bf(v.x); p.u[1] = f2bf(v.y); p.u[2] = f2bf(v.z); p.u[3] = f2bf(v.w);
        ((uint2*)out)[i] = p.q;
    } else {
        int i = (bid - 8192) * 256 + tid;       // 65536 total
        int n = i >> 5, d = i & 31;
        float inv = powf(10000.0f, -(float)(2 * d) * (1.0f / 64.0f));
        float a = (float)n * inv;
        float s, c;
        sincosf(a, &s, &c);
        cosT[i] = c; sinT[i] = s;
    }
}

// ---------------------- GEMM C = A * Bt^T  (bf16 MFMA) ---------------------
// Tile BM x 128, 4 waves (2x2), BK=32, 16x16x32 bf16 MFMA (m97 shape, R1-proven).
// MODE 0 (BM=128): qkv epilogue (RoPE; Q scaled by log2e/8; V transposed via
//                  LDS with key-permuted layout: slot s holds key swap23(s))
// MODE 1 (BM=64):  out epilogue (+bias, fp32 store)
template <int MODE, int BM>
__global__ __launch_bounds__(256) void gemm_bt(
    const unsigned short* __restrict__ A, const unsigned short* __restrict__ Bt,
    int M, int N, int K,
    unsigned short* __restrict__ Qbuf, unsigned short* __restrict__ Kbuf,
    unsigned short* __restrict__ Vt,
    const float* __restrict__ cosT, const float* __restrict__ sinT,
    float* __restrict__ Cout, const float* __restrict__ bias) {
    constexpr int WM = BM / 2;       // rows per wave
    constexpr int MI = WM / 16;      // A-frag count per wave
    __shared__ __align__(16) unsigned short As[BM * 32];
    __shared__ __align__(16) unsigned short Bs[128 * 32];
    const int tid = threadIdx.x;
    const int wave = tid >> 6, lane = tid & 63, g = lane >> 4, li = lane & 15;
    const int wr = wave >> 1, wc = wave & 1;
    const int m0 = blockIdx.y * BM, n0 = blockIdx.x * 128;

    f32x4 acc[MI][4] = {};
    const int nK = K >> 5;
    for (int kk = 0; kk < nK; ++kk) {
#pragma unroll
        for (int i = 0; i < BM / 64; ++i) {     // A tile: BM*4 chunks of 16B
            int cb = i * 256 + wave * 64;
            int c = cb + lane;
            int r = c >> 2, k0 = (c & 3) * 8;
            gload16(A + (size_t)(m0 + r) * K + kk * 32 + k0, &As[cb * 8]);
        }
#pragma unroll
        for (int i = 0; i < 2; ++i) {           // B tile: 512 chunks
            int cb = i * 256 + wave * 64;
            int c = cb + lane;
            int r = c >> 2, k0 = (c & 3) * 8;
            gload16(Bt + (size_t)(n0 + r) * K + kk * 32 + k0, &Bs[cb * 8]);
        }
        __syncthreads();
        short8 af[MI], bf[4];
#pragma unroll
        for (int mi = 0; mi < MI; ++mi)
            af[mi] = *(const short8*)&As[(wr * WM + mi * 16 + li) * 32 + g * 8];
#pragma unroll
        for (int ni = 0; ni < 4; ++ni)
            bf[ni] = *(const short8*)&Bs[(wc * 64 + ni * 16 + li) * 32 + g * 8];
#pragma unroll
        for (int mi = 0; mi < MI; ++mi)
#pragma unroll
            for (int ni = 0; ni < 4; ++ni)
                acc[mi][ni] = __builtin_amdgcn_mfma_f32_16x16x32_bf16(
                    asb(af[mi]), asb(bf[ni]), acc[mi][ni], 0, 0, 0);
        __syncthreads();
    }

    if (MODE == 1) {
#pragma unroll
        for (int mi = 0; mi < MI; ++mi) {
            int row = m0 + wr * WM + mi * 16 + 4 * g;
#pragma unroll
            for (int ni = 0; ni < 4; ++ni) {
                int col = n0 + wc * 64 + ni * 16 + li;
                float b = bias[col];
#pragma unroll
                for (int r = 0; r < 4; ++r)
                    Cout[(size_t)(row + r) * N + col] = acc[mi][ni][r] + b;
            }
        }
    } else {
        // three = fb/1024 is block-uniform; hh differs per wave-column
        const int fb = n0 + wc * 64;
        const int three = fb >> 10;
        const int hh = (fb & 1023) >> 6;
        const int bq = m0 >> 11;
        const int nb0 = m0 & 2047;
        const size_t bh = (size_t)(bq * 16 + hh);
        if (three < 2) {
            // Q/K with RoPE; Q scaled by log2e/8 (base-2 softmax fold)
#pragma unroll
            for (int mi = 0; mi < MI; ++mi) {
#pragma unroll
                for (int r = 0; r < 4; ++r) {
                    int n = nb0 + wr * WM + mi * 16 + 4 * g + r;
                    float v0 = acc[mi][0][r], v1 = acc[mi][1][r];
                    float v2 = acc[mi][2][r], v3 = acc[mi][3][r];
                    float c0 = cosT[n * 32 + li],      s0 = sinT[n * 32 + li];
                    float c1 = cosT[n * 32 + 16 + li], s1 = sinT[n * 32 + 16 + li];
                    float o0 = v0 * c0 - v2 * s0;
                    float o2 = v2 * c0 + v0 * s0;
                    float o1 = v1 * c1 - v3 * s1;
                    float o3 = v3 * c1 + v1 * s1;
                    if (three == 0) {
                        const float qs = 0.18033688f;  // 0.125 * log2(e)
                        o0 *= qs; o1 *= qs; o2 *= qs; o3 *= qs;
                    }
                    unsigned short* dst = (three == 0 ? Qbuf : Kbuf) + (bh * 2048 + n) * 64;
                    dst[li] = f2bf(o0); dst[16 + li] = f2bf(o1);
                    dst[32 + li] = f2bf(o2); dst[48 + li] = f2bf(o3);
                }
            }
        } else {
            // V: per-wave transpose via LDS (reuse As), with key-permutation
            // swap23 within each 16-token group (PV sigma-layout, see attnk)
            unsigned short* vtw = As + wave * 1024;        // [64 d][16 slots]
            const int gsw = ((g & 1) << 1) | (g >> 1);     // swap 2-bit halves
#pragma unroll
            for (int mi = 0; mi < MI; ++mi) {
                __syncthreads();               // prev-mi reads fully done
#pragma unroll
                for (int ni = 0; ni < 4; ++ni)
#pragma unroll
                    for (int r = 0; r < 4; ++r)
                        vtw[(ni * 16 + li) * 16 + 4 * gsw + r] = f2bf(acc[mi][ni][r]);
                __syncthreads();               // transpose writes visible
                uint4 lo = *(const uint4*)&vtw[lane * 16];
                uint4 hi = *(const uint4*)&vtw[lane * 16 + 8];
                int nbase = nb0 + wr * WM + mi * 16;
                unsigned short* dst = Vt + (bh * 64 + lane) * 2048 + nbase;
                *(uint4*)dst = lo;
                *(uint4*)(dst + 8) = hi;
            }
        }
    }
}

// ------------------------------ attention ---------------------------------
// KV-split x2, fixed-base softmax (p=exp2(s)), partial (O,l) outputs.
// R8: VALU diet. One 32KB LDS arena: K[cur] at cur*8192, V[cur] at
// 16384+cur*8192. Tile loop unrolled by parity so every ds_read is
// base-register + immediate offset; per-lane swizzled bases precomputed;
// MFMA chains start from a hoisted zero vector (no per-tile acc init);
// global pointers advanced incrementally. Schedule identical to R6/R7:
// compute(kt) | stage(kt+1) | barrier | issue(kt+2).
__global__ __launch_bounds__(256) void attnk(
    const unsigned short* __restrict__ Qb, const unsigned short* __restrict__ Kb,
    const unsigned short* __restrict__ Vt, unsigned short* __restrict__ Op,
    float* __restrict__ lp) {
    __shared__ __align__(16) char arena[32768];
    const int tid = threadIdx.x, wave = tid >> 6, lane = tid & 63;
    const int h = lane >> 5, li = lane & 31;

    // XCD-bijective swizzle: 1024 blocks / 8 XCDs -> 4 heads per XCD (2MB L2)
    const int fid = blockIdx.y * 32 + blockIdx.x;
    const int logical = (fid & 7) * 128 + (fid >> 3);
    const int bh = logical >> 5;
    const int s  = (logical >> 4) & 1;
    const int qt = logical & 15;
    const int q0 = qt * 128 + wave * 32;

    // Q B-frags: lane holds Q[q0+li][16c + 8h + j]  (pre-scaled by log2e/8)
    bf16x8 qf0, qf1, qf2, qf3;
    {
        const unsigned short* qp = Qb + ((size_t)bh * 2048 + q0 + li) * 64;
        qf0 = asb(*(const short8*)(qp + 0 * 16 + h * 8));
        qf1 = asb(*(const short8*)(qp + 1 * 16 + h * 8));
        qf2 = asb(*(const short8*)(qp + 2 * 16 + h * 8));
        qf3 = asb(*(const short8*)(qp + 3 * 16 + h * 8));
    }

    // per-lane swizzled READ bases (bytes into arena), c=0..3:
    //   ka_c = li*128 + ((2c+h)^(li&7))*16 ; +4096 = rows 32..63 ;
    //   +CUR*8192 = buffer ; +16384 = V arena
    const int lix = li & 7;
    const int ka0 = li * 128 + (((0 + h) ^ lix) * 16);
    const int ka1 = li * 128 + (((2 + h) ^ lix) * 16);
    const int ka2 = li * 128 + (((4 + h) ^ lix) * 16);
    const int ka3 = li * 128 + (((6 + h) ^ lix) * 16);

    // WRITE offsets (bytes): chunk-swizzled, matches read XOR
    const int kw0 = swzc(tid) * 16;
    const int kw1 = swzc(tid + 256) * 16;

    // incremental global pointers (advance by constant stride per issue)
    const int r0 = tid >> 3, r1 = (tid + 256) >> 3, cc = tid & 7;
    const uint4* kpa = (const uint4*)(Kb + (size_t)bh * 2048 * 64) + (size_t)s * 16 * 512 + tid;
    const uint4* kpb = kpa + 256;
    const uint4* vpa = (const uint4*)Vt + ((size_t)bh * 64 + r0) * 256 + cc + (size_t)s * 16 * 8;
    const uint4* vpb = (const uint4*)Vt + ((size_t)bh * 64 + r1) * 256 + cc + (size_t)s * 16 * 8;

    uint4 kr0, kr1, vr0, vr1;

    const f32x16 z16 = {};           // hoisted MFMA C-operand zero
    f32x16 o0 = {}, o1 = {};
    float l_ = 0.f;

    // prologue: issue+stage tile 0 into buf0; barrier; issue tile 1
    kr0 = kpa[0]; kr1 = kpb[0]; vr0 = vpa[0]; vr1 = vpb[0];
    kpa += 512; kpb += 512; vpa += 8; vpb += 8;
    *(uint4*)(arena + kw0) = kr0;
    *(uint4*)(arena + kw1) = kr1;
    *(uint4*)(arena + 16384 + kw0) = vr0;
    *(uint4*)(arena + 16384 + kw1) = vr1;
    __syncthreads();
    kr0 = kpa[0]; kr1 = kpb[0]; vr0 = vpa[0]; vr1 = vpb[0];
    kpa += 512; kpb += 512; vpa += 8; vpb += 8;

#define QK_PAIR(CUR, KA, QF)                                                    \
    {                                                                           \
        bf16x8 kf0 = asb(*(const short8*)(arena + (KA) + (CUR) * 8192));        \
        bf16x8 kf1 = asb(*(const short8*)(arena + (KA) + (CUR) * 8192 + 4096)); \
        s0 = __builtin_amdgcn_mfma_f32_32x32x16_bf16(kf0, QF, s0, 0, 0, 0);     \
        s1 = __builtin_amdgcn_mfma_f32_32x32x16_bf16(kf1, QF, s1, 0, 0, 0);     \
    }

#define TILE_BODY(CUR, DO_STAGE, DO_ISSUE)                                      \
    {                                                                           \
        f32x16 s0, s1;                                                          \
        {   /* QK^T: chains start from hoisted zero */                          \
            bf16x8 kf0 = asb(*(const short8*)(arena + ka0 + (CUR) * 8192));     \
            bf16x8 kf1 = asb(*(const short8*)(arena + ka0 + (CUR) * 8192 + 4096)); \
            s0 = __builtin_amdgcn_mfma_f32_32x32x16_bf16(kf0, qf0, z16, 0, 0, 0); \
            s1 = __builtin_amdgcn_mfma_f32_32x32x16_bf16(kf1, qf0, z16, 0, 0, 0); \
        }                                                                       \
        QK_PAIR(CUR, ka1, qf1)                                                  \
        QK_PAIR(CUR, ka2, qf2)                                                  \
        QK_PAIR(CUR, ka3, qf3)                                                  \
        float sm0 = 0.f, sm1 = 0.f;                                             \
        _Pragma("unroll")                                                       \
        for (int r = 0; r < 16; ++r) {                                          \
            float p0 = __builtin_exp2f(s0[r]); s0[r] = p0; sm0 += p0;           \
            float p1 = __builtin_exp2f(s1[r]); s1[r] = p1; sm1 += p1;           \
        }                                                                       \
        l_ += sm0 + sm1;                                                        \
        uint32_t w0[8], w1[8];                                                  \
        _Pragma("unroll")                                                       \
        for (int m = 0; m < 8; ++m) {                                           \
            w0[m] = pk2(s0[2 * m], s0[2 * m + 1]);                              \
            w1[m] = pk2(s1[2 * m], s1[2 * m + 1]);                              \
        }                                                                       \
        {   bf16x8 pf = asb4(w0[0], w0[1], w0[2], w0[3]);                       \
            bf16x8 vf0 = asb(*(const short8*)(arena + ka0 + 16384 + (CUR) * 8192)); \
            bf16x8 vf1 = asb(*(const short8*)(arena + ka0 + 16384 + (CUR) * 8192 + 4096)); \
            o0 = __builtin_amdgcn_mfma_f32_32x32x16_bf16(pf, vf0, o0, 0, 0, 0); \
            o1 = __builtin_amdgcn_mfma_f32_32x32x16_bf16(pf, vf1, o1, 0, 0, 0); } \
        {   bf16x8 pf = asb4(w0[4], w0[5], w0[6], w0[7]);                       \
            bf16x8 vf0 = asb(*(const short8*)(arena + ka1 + 16384 + (CUR) * 8192)); \
            bf16x8 vf1 = asb(*(const short8*)(arena + ka1 + 16384 + (CUR) * 8192 + 4096)); \
            o0 = __builtin_amdgcn_mfma_f32_32x32x16_bf16(pf, vf0, o0, 0, 0, 0); \
            o1 = __builtin_amdgcn_mfma_f32_32x32x16_bf16(pf, vf1, o1, 0, 0, 0); } \
        {   bf16x8 pf = asb4(w1[0], w1[1], w1[2], w1[3]);                       \
            bf16x8 vf0 = asb(*(const short8*)(arena + ka2 + 16384 + (CUR) * 8192)); \
            bf16x8 vf1 = asb(*(const short8*)(arena + ka2 + 16384 + (CUR) * 8192 + 4096)); \
            o0 = __builtin_amdgcn_mfma_f32_32x32x16_bf16(pf, vf0, o0, 0, 0, 0); \
            o1 = __builtin_amdgcn_mfma_f32_32x32x16_bf16(pf, vf1, o1, 0, 0, 0); } \
        {   bf16x8 pf = asb4(w1[4], w1[5], w1[6], w1[7]);                       \
            bf16x8 vf0 = asb(*(const short8*)(arena + ka3 + 16384 + (CUR) * 8192)); \
            bf16x8 vf1 = asb(*(const short8*)(arena + ka3 + 16384 + (CUR) * 8192 + 4096)); \
            o0 = __builtin_amdgcn_mfma_f32_32x32x16_bf16(pf, vf0, o0, 0, 0, 0); \
            o1 = __builtin_amdgcn_mfma_f32_32x32x16_bf16(pf, vf1, o1, 0, 0, 0); } \
        if (DO_STAGE) {                                                         \
            const int NB = ((CUR) ^ 1) * 8192;                                  \
            *(uint4*)(arena + NB + kw0) = kr0;                                  \
            *(uint4*)(arena + NB + kw1) = kr1;                                  \
            *(uint4*)(arena + 16384 + NB + kw0) = vr0;                          \
            *(uint4*)(arena + 16384 + NB + kw1) = vr1;                          \
            __syncthreads();                                                    \
            if (DO_ISSUE) {                                                     \
                kr0 = kpa[0]; kr1 = kpb[0]; vr0 = vpa[0]; vr1 = vpb[0];         \
                kpa += 512; kpb += 512; vpa += 8; vpb += 8;                     \
            }                                                                   \
        }                                                                       \
    }

    for (int p = 0; p < 7; ++p) {       // tiles 0..13 (full stage+issue)
        TILE_BODY(0, 1, 1)
        TILE_BODY(1, 1, 1)
    }
    TILE_BODY(0, 1, 0)                  // tile 14: stage 15, no issue
    TILE_BODY(1, 0, 0)                  // tile 15: compute only

#undef TILE_BODY
#undef QK_PAIR

    // epilogue: store UNNORMALIZED partial O (bf16) + partial l (f32)
    const size_t obase = ((size_t)s * 32 + bh) * 2048;
#pragma unroll
    for (int r = 0; r < 16; ++r) {
        int qrow = (r & 3) + 8 * (r >> 2) + 4 * h;
        int n = q0 + qrow;
        unsigned short* dst = Op + (obase + n) * 64 + li;
        dst[0]  = f2bf(o0[r]);
        dst[32] = f2bf(o1[r]);
    }
    float lc = l_ + __shfl_xor(l_, 32);
    if (h == 0) lp[obase + q0 + li] = lc;
}

// ------------------------- combine split partials --------------------------
// Obuf[b][n][hh][64] = (O0 + O1) / (l0 + l1), bf16. 524288 threads.
__global__ __launch_bounds__(256) void combk(
    const unsigned short* __restrict__ Op, const float* __restrict__ lp,
    unsigned short* __restrict__ Obuf) {
    int t = blockIdx.x * 256 + threadIdx.x;
    int d8 = t & 7, hh = (t >> 3) & 15, n = (t >> 7) & 2047, b = t >> 18;
    size_t row = ((size_t)(b * 16 + hh)) * 2048 + n;
    float linv = 1.0f / (lp[row] + lp[row + 65536]);
    const uint4 a = *(const uint4*)(Op + row * 64 + d8 * 8);
    const uint4 c = *(const uint4*)(Op + 4194304 + row * 64 + d8 * 8);
    uint4 o;
    o.x = pk2(linv * (bflo(a.x) + bflo(c.x)), linv * (bfhi(a.x) + bfhi(c.x)));
    o.y = pk2(linv * (bflo(a.y) + bflo(c.y)), linv * (bfhi(a.y) + bfhi(c.y)));
    o.z = pk2(linv * (bflo(a.z) + bflo(c.z)), linv * (bfhi(a.z) + bfhi(c.z)));
    o.w = pk2(linv * (bflo(a.w) + bflo(c.w)), linv * (bfhi(a.w) + bfhi(c.w)));
    *(uint4*)(Obuf + ((size_t)(b * 2048 + n)) * 1024 + hh * 64 + d8 * 8) = o;
}

// ------------------------------- launch ------------------------------------
extern "C" void kernel_launch(void* const* d_in, const int* in_sizes, int n_in,
                              void* d_out, int out_size, void* d_ws, size_t ws_size,
                              hipStream_t stream) {
    const float* x    = (const float*)d_in[0];
    const float* Wqkv = (const float*)d_in[1];
    const float* Wout = (const float*)d_in[2];
    const float* bout = (const float*)d_in[3];
    float* out = (float*)d_out;
    char* ws = (char*)d_ws;

    size_t off = 0;
    unsigned short* xb    = (unsigned short*)(ws + off);
    unsigned short* Obuf  = xb;                                      // alias
    off += (size_t)4096 * 1024 * 2;
    unsigned short* wqkvb = (unsigned short*)(ws + off); off += (size_t)3072 * 1024 * 2;
    unsigned short* woutb = (unsigned short*)(ws + off); off += (size_t)1024 * 1024 * 2;
    float* cosT = (float*)(ws + off); off += (size_t)2048 * 32 * 4;
    float* sinT = (float*)(ws + off); off += (size_t)2048 * 32 * 4;
    unsigned short* Qbuf = (unsigned short*)(ws + off); off += (size_t)32 * 2048 * 64 * 2;
    unsigned short* Kbuf = (unsigned short*)(ws + off); off += (size_t)32 * 2048 * 64 * 2;
    unsigned short* Vt   = (unsigned short*)(ws + off); off += (size_t)32 * 64 * 2048 * 2;
    unsigned short* Op   = (unsigned short*)(ws + off); off += (size_t)2 * 32 * 2048 * 64 * 2;
    float* lp            = (float*)(ws + off);          off += (size_t)2 * 32 * 2048 * 4;

    prepk<<<8448, 256, 0, stream>>>(x, Wqkv, Wout, xb, wqkvb, woutb, cosT, sinT);

    gemm_bt<0, 128><<<dim3(24, 32), 256, 0, stream>>>(
        xb, wqkvb, 4096, 3072, 1024, Qbuf, Kbuf, Vt, cosT, sinT, nullptr, nullptr);

    attnk<<<dim3(32, 32), 256, 0, stream>>>(Qbuf, Kbuf, Vt, Op, lp);

    combk<<<2048, 256, 0, stream>>>(Op, lp, Obuf);

    gemm_bt<1, 64><<<dim3(8, 64), 256, 0, stream>>>(
        Obuf, woutb, 4096, 1024, 1024, nullptr, nullptr, nullptr, nullptr, nullptr,
        out, bout);
}